// Round 2
// baseline (465.955 us; speedup 1.0000x reference)
//
#include <hip/hip_runtime.h>

#define CHN 256
#define GRP 4
#define GCH 64
#define PTS 9
#define NBATCH 8
#define HSZ 64
#define WSZ 64
#define LSZ (HSZ*WSZ)

// Generic tiled f32 GEMM: C[M,N] = A[M,K] @ B[K,N] + bias[N]
// A row-major, B row-major. Requires M % (16*TM) == 0, K % 16 == 0.
// N may be ragged (guarded). 256 threads.
template<int TM, int TN>
__global__ __launch_bounds__(256) void gemm_bias(const float* __restrict__ A,
    const float* __restrict__ B, const float* __restrict__ bias,
    float* __restrict__ C, int M, int N, int K) {
  constexpr int BM = 16 * TM, BN = 16 * TN, BK = 16;
  __shared__ float As[BK][BM + 4];   // transposed A tile: As[k][m]
  __shared__ float Bs[BK][BN + 4];   // Bs[k][n]
  const int tid = threadIdx.x;
  const int row0 = blockIdx.y * BM;
  const int col0 = blockIdx.x * BN;
  const int tx = tid & 15, ty = tid >> 4;

  float acc[TM][TN];
#pragma unroll
  for (int i = 0; i < TM; ++i)
#pragma unroll
    for (int j = 0; j < TN; ++j) acc[i][j] = 0.f;

  for (int k0 = 0; k0 < K; k0 += BK) {
    // ---- load A tile (BM x BK), transposed into As ----
#pragma unroll
    for (int i = 0; i < (BM * BK) / (256 * 4); ++i) {
      int s = tid + i * 256;
      int m = s >> 2, kq = (s & 3) << 2;
      const float4 a = *(const float4*)&A[(size_t)(row0 + m) * K + k0 + kq];
      As[kq + 0][m] = a.x; As[kq + 1][m] = a.y;
      As[kq + 2][m] = a.z; As[kq + 3][m] = a.w;
    }
    // ---- load B tile (BK x BN) ----
#pragma unroll
    for (int i = 0; i < (BK * BN) / (256 * 4); ++i) {
      int s = tid + i * 256;
      int kk = s / (BN / 4);
      int nn = (s % (BN / 4)) << 2;
      int col = col0 + nn;
      const float* Brow = &B[(size_t)(k0 + kk) * N];
      float4 b;
      if (col + 3 < N) {
        b = *(const float4*)&Brow[col];
      } else {
        b.x = (col + 0 < N) ? Brow[col + 0] : 0.f;
        b.y = (col + 1 < N) ? Brow[col + 1] : 0.f;
        b.z = (col + 2 < N) ? Brow[col + 2] : 0.f;
        b.w = (col + 3 < N) ? Brow[col + 3] : 0.f;
      }
      *(float4*)&Bs[kk][nn] = b;
    }
    __syncthreads();

#pragma unroll
    for (int k = 0; k < BK; ++k) {
      float a[TM], b[TN];
      *(float4*)&a[0] = *(const float4*)&As[k][ty * 4];
      if constexpr (TM == 8)
        *(float4*)&a[4] = *(const float4*)&As[k][BM / 2 + ty * 4];
      *(float4*)&b[0] = *(const float4*)&Bs[k][tx * 4];
      if constexpr (TN == 8)
        *(float4*)&b[4] = *(const float4*)&Bs[k][BN / 2 + tx * 4];
#pragma unroll
      for (int i = 0; i < TM; ++i)
#pragma unroll
        for (int j = 0; j < TN; ++j) acc[i][j] += a[i] * b[j];
    }
    __syncthreads();
  }

  // ---- epilogue: bias + store, float4 fast path per 4-col chunk ----
#pragma unroll
  for (int i = 0; i < TM; ++i) {
    int row;
    if constexpr (TM == 8) row = row0 + ((i < 4) ? (ty * 4 + i) : (BM / 2 + ty * 4 + i - 4));
    else                   row = row0 + ty * 4 + i;
    float* Crow = &C[(size_t)row * N];
#pragma unroll
    for (int jq = 0; jq < TN / 4; ++jq) {
      int col;
      if constexpr (TN == 8) col = col0 + ((jq == 0) ? (tx * 4) : (BN / 2 + tx * 4));
      else                   col = col0 + tx * 4;
      if (col + 3 < N) {
        float4 r;
        r.x = acc[i][jq * 4 + 0] + bias[col + 0];
        r.y = acc[i][jq * 4 + 1] + bias[col + 1];
        r.z = acc[i][jq * 4 + 2] + bias[col + 2];
        r.w = acc[i][jq * 4 + 3] + bias[col + 3];
        *(float4*)&Crow[col] = r;
      } else {
#pragma unroll
        for (int j = 0; j < 4; ++j)
          if (col + j < N) Crow[col + j] = acc[i][jq * 4 + j] + bias[col + j];
      }
    }
  }
}

// Deformable sampling. One wave per (n, hw, g); lane = channel within group.
// val: (N, L, 256)   off: (N, L, 72)   msk: (N, L, 36)   out: (N, L, 256)
// Padded-coordinate algebra: sample position px = w+1+dx+off_x, py = h+1+dy+off_y
// (padded image is 66x66 with a zero ring); a corner contributes iff it lies in
// the interior [1,64]^2 (invalid -> weight 0, pad ring -> value 0; both give 0).
__global__ __launch_bounds__(256) void dcn_sample(const float* __restrict__ val,
    const float* __restrict__ off, const float* __restrict__ msk,
    float* __restrict__ out) {
  const int wid = threadIdx.x >> 6;
  const int lane = threadIdx.x & 63;
  const int q = blockIdx.x * 4 + wid;      // ((n*L + hw)*G + g)
  const int g = q & 3;
  const int hw = (q >> 2) & (LSZ - 1);
  const int n = q >> 14;                   // G*L = 2^14
  const int h = hw >> 6, w = hw & 63;

  const float* offp = off + (size_t)(n * LSZ + hw) * 72 + g * 18;
  const float* mskp = msk + (size_t)(n * LSZ + hw) * 36 + g * 9;
  const float* vbase = val + (size_t)n * LSZ * CHN + g * GCH + lane;

  float acc = 0.f;
#pragma unroll
  for (int p = 0; p < PTS; ++p) {
    const int dx = p / 3 - 1, dy = p % 3 - 1;   // x-major flatten (torch 'ij' over (w,h))
    const float ox = offp[p * 2 + 0];
    const float oy = offp[p * 2 + 1];
    const float m = mskp[p];
    const float px = (float)(w + 1 + dx) + ox;
    const float py = (float)(h + 1 + dy) + oy;
    const float fx = floorf(px), fy = floorf(py);
    const int x0 = (int)fx, y0 = (int)fy;
    const float wx = px - fx, wy = py - fy;
    const float w00 = m * (1.f - wx) * (1.f - wy);
    const float w10 = m * wx * (1.f - wy);
    const float w01 = m * (1.f - wx) * wy;
    const float w11 = m * wx * wy;
    {
      const int xi = x0, yi = y0;
      if (xi >= 1 && xi <= 64 && yi >= 1 && yi <= 64)
        acc += w00 * vbase[(size_t)((yi - 1) * WSZ + (xi - 1)) * CHN];
    }
    {
      const int xi = x0 + 1, yi = y0;
      if (xi >= 1 && xi <= 64 && yi >= 1 && yi <= 64)
        acc += w10 * vbase[(size_t)((yi - 1) * WSZ + (xi - 1)) * CHN];
    }
    {
      const int xi = x0, yi = y0 + 1;
      if (xi >= 1 && xi <= 64 && yi >= 1 && yi <= 64)
        acc += w01 * vbase[(size_t)((yi - 1) * WSZ + (xi - 1)) * CHN];
    }
    {
      const int xi = x0 + 1, yi = y0 + 1;
      if (xi >= 1 && xi <= 64 && yi >= 1 && yi <= 64)
        acc += w11 * vbase[(size_t)((yi - 1) * WSZ + (xi - 1)) * CHN];
    }
  }
  out[(size_t)(n * LSZ + hw) * CHN + g * GCH + lane] = acc;
}

extern "C" void kernel_launch(void* const* d_in, const int* in_sizes, int n_in,
                              void* d_out, int out_size, void* d_ws, size_t ws_size,
                              hipStream_t stream) {
  const float* x        = (const float*)d_in[0];
  const float* w_value  = (const float*)d_in[1];
  const float* b_value  = (const float*)d_in[2];
  const float* w_offset = (const float*)d_in[3];
  const float* b_offset = (const float*)d_in[4];
  const float* w_mask   = (const float*)d_in[5];
  const float* b_mask   = (const float*)d_in[6];
  const float* w_out    = (const float*)d_in[7];
  const float* b_out    = (const float*)d_in[8];
  float* out = (float*)d_out;

  const int M = NBATCH * LSZ;          // 32768
  float* ws    = (float*)d_ws;
  float* value = ws;                               // M*256
  float* offv  = value + (size_t)M * CHN;          // M*72
  float* mskv  = offv  + (size_t)M * 72;           // M*36
  float* yv    = mskv  + (size_t)M * 36;           // M*256

  dim3 blk(256);
  // value GEMM: 32768 x 256 x 256, 128x128 tiles
  gemm_bias<8, 8><<<dim3(CHN / 128, M / 128), blk, 0, stream>>>(
      x, w_value, b_value, value, M, CHN, CHN);
  // offset GEMM: 32768 x 72 x 256, 64x64 tiles
  gemm_bias<4, 4><<<dim3((72 + 63) / 64, M / 64), blk, 0, stream>>>(
      x, w_offset, b_offset, offv, M, 72, CHN);
  // mask GEMM: 32768 x 36 x 256
  gemm_bias<4, 4><<<dim3((36 + 63) / 64, M / 64), blk, 0, stream>>>(
      x, w_mask, b_mask, mskv, M, 36, CHN);
  // deformable sampling: one wave per (n,hw,g)
  dcn_sample<<<dim3(M * GRP / 4), blk, 0, stream>>>(value, offv, mskv, yv);
  // output GEMM: 32768 x 256 x 256
  gemm_bias<8, 8><<<dim3(CHN / 128, M / 128), blk, 0, stream>>>(
      yv, w_out, b_out, out, M, CHN, CHN);
}

// Round 4
// 276.797 us; speedup vs baseline: 1.6834x; 1.6834x over previous
//
#include <hip/hip_runtime.h>
#include <hip/hip_bf16.h>

#define CHN 256
#define GRP 4
#define GCH 64
#define PTS 9
#define NBATCH 8
#define HSZ 64
#define WSZ 64
#define LSZ (HSZ*WSZ)

typedef __attribute__((ext_vector_type(4))) float f32x4;
typedef __attribute__((ext_vector_type(8))) short bf16x8;

// Split a pair of f32 into packed bf16 hi and lo words (hi in low ushort = first elem).
__device__ inline void split_pk(float a, float b, unsigned& hi, unsigned& lo) {
  float2 p; p.x = a; p.y = b;
  __hip_bfloat162 h = __float22bfloat162_rn(p);
  float2 r; r.x = a - __bfloat162float(h.x); r.y = b - __bfloat162float(h.y);
  __hip_bfloat162 l = __float22bfloat162_rn(r);
  hi = *reinterpret_cast<unsigned*>(&h);
  lo = *reinterpret_cast<unsigned*>(&l);
}

// f32 GEMM via split-bf16 MFMA: C[M,N] = A[M,K] @ B[K,N] + bias[N].
// A,B,C row-major f32. Requires M%128==0, N%128==0, K%32==0.
// 256 threads = 4 waves (2x2), each wave owns a 64x64 output sub-tile
// (4x4 fragments of 16x16, mfma_f32_16x16x32_bf16).
// f32 = bf16_hi + bf16_lo; A*B ~= AhBh + AhBl + AlBh (AlBl ~2^-32, dropped).
__global__ __launch_bounds__(256) void gemm_mfma_split(
    const float* __restrict__ A, const float* __restrict__ B,
    const float* __restrict__ bias, float* __restrict__ C,
    int M, int N, int K) {
  constexpr int BM = 128, BN = 128, BK = 32, KP = 40; // KP: pad to 80B rows (16B-aligned b128 reads)
  __shared__ unsigned short Ah[BM * KP], Al[BM * KP];  // [M][K] bf16 tiles
  __shared__ unsigned short Bh[BN * KP], Bl[BN * KP];  // [N][K] (B^T) bf16 tiles
  const int tid = threadIdx.x;
  const int row0 = blockIdx.y * BM, col0 = blockIdx.x * BN;
  const int wid = tid >> 6, lane = tid & 63;
  const int wr = wid >> 1, wc = wid & 1;      // 2x2 wave grid
  const int lrow = lane & 15, slab = lane >> 4; // fragment row/col, K-slab

  f32x4 acc[4][4] = {};

  for (int k0 = 0; k0 < K; k0 += BK) {
    // ---- stage A tile 128x32 f32 -> Ah/Al [M][K] ----
#pragma unroll
    for (int q = 0; q < 4; ++q) {
      int s = tid + q * 256;           // 1024 float4 slots
      int m = s >> 3, kq = (s & 7) << 2;
      float4 a = *(const float4*)&A[(size_t)(row0 + m) * K + k0 + kq];
      unsigned h01, l01, h23, l23;
      split_pk(a.x, a.y, h01, l01);
      split_pk(a.z, a.w, h23, l23);
      *(unsigned*)&Ah[m * KP + kq]     = h01;
      *(unsigned*)&Ah[m * KP + kq + 2] = h23;
      *(unsigned*)&Al[m * KP + kq]     = l01;
      *(unsigned*)&Al[m * KP + kq + 2] = l23;
    }
    // ---- stage B tile 32x128 f32 -> Bh/Bl transposed [N][K] ----
#pragma unroll
    for (int q = 0; q < 4; ++q) {
      int s = tid + q * 256;
      int kk = s >> 5, nn = (s & 31) << 2;
      float4 b = *(const float4*)&B[(size_t)(k0 + kk) * N + col0 + nn];
      unsigned h01, l01, h23, l23;
      split_pk(b.x, b.y, h01, l01);
      split_pk(b.z, b.w, h23, l23);
      Bh[(nn + 0) * KP + kk] = (unsigned short)(h01 & 0xffff);
      Bh[(nn + 1) * KP + kk] = (unsigned short)(h01 >> 16);
      Bh[(nn + 2) * KP + kk] = (unsigned short)(h23 & 0xffff);
      Bh[(nn + 3) * KP + kk] = (unsigned short)(h23 >> 16);
      Bl[(nn + 0) * KP + kk] = (unsigned short)(l01 & 0xffff);
      Bl[(nn + 1) * KP + kk] = (unsigned short)(l01 >> 16);
      Bl[(nn + 2) * KP + kk] = (unsigned short)(l23 & 0xffff);
      Bl[(nn + 3) * KP + kk] = (unsigned short)(l23 >> 16);
    }
    __syncthreads();

    // ---- fragment loads: 8 contiguous K-elems per lane (ds_read_b128) ----
    bf16x8 ah[4], al[4], bh[4], bl[4];
#pragma unroll
    for (int i = 0; i < 4; ++i) {
      ah[i] = *(const bf16x8*)&Ah[(wr * 64 + i * 16 + lrow) * KP + slab * 8];
      al[i] = *(const bf16x8*)&Al[(wr * 64 + i * 16 + lrow) * KP + slab * 8];
      bh[i] = *(const bf16x8*)&Bh[(wc * 64 + i * 16 + lrow) * KP + slab * 8];
      bl[i] = *(const bf16x8*)&Bl[(wc * 64 + i * 16 + lrow) * KP + slab * 8];
    }
#pragma unroll
    for (int m = 0; m < 4; ++m)
#pragma unroll
      for (int n = 0; n < 4; ++n) {
        acc[m][n] = __builtin_amdgcn_mfma_f32_16x16x32_bf16(ah[m], bh[n], acc[m][n], 0, 0, 0);
        acc[m][n] = __builtin_amdgcn_mfma_f32_16x16x32_bf16(ah[m], bl[n], acc[m][n], 0, 0, 0);
        acc[m][n] = __builtin_amdgcn_mfma_f32_16x16x32_bf16(al[m], bh[n], acc[m][n], 0, 0, 0);
      }
    __syncthreads();
  }

  // ---- epilogue: C/D layout col=lane&15, row=(lane>>4)*4+reg (m89-verified) ----
#pragma unroll
  for (int m = 0; m < 4; ++m)
#pragma unroll
    for (int n = 0; n < 4; ++n) {
      const int col = col0 + wc * 64 + n * 16 + lrow;
      const float bv = bias[col];
#pragma unroll
      for (int r = 0; r < 4; ++r) {
        const int row = row0 + wr * 64 + m * 16 + slab * 4 + r;
        C[(size_t)row * N + col] = acc[m][n][r] + bv;
      }
    }
}

// Tiled f32 VALU GEMM for the skinny offset/mask projections (N=72/36).
template<int TM, int TN>
__global__ __launch_bounds__(256) void gemm_bias(const float* __restrict__ A,
    const float* __restrict__ B, const float* __restrict__ bias,
    float* __restrict__ C, int M, int N, int K) {
  constexpr int BM = 16 * TM, BN = 16 * TN, BK = 16;
  __shared__ float As[BK][BM + 4];
  __shared__ float Bs[BK][BN + 4];
  const int tid = threadIdx.x;
  const int row0 = blockIdx.y * BM;
  const int col0 = blockIdx.x * BN;
  const int tx = tid & 15, ty = tid >> 4;

  float acc[TM][TN];
#pragma unroll
  for (int i = 0; i < TM; ++i)
#pragma unroll
    for (int j = 0; j < TN; ++j) acc[i][j] = 0.f;

  for (int k0 = 0; k0 < K; k0 += BK) {
#pragma unroll
    for (int i = 0; i < (BM * BK) / (256 * 4); ++i) {
      int s = tid + i * 256;
      int m = s >> 2, kq = (s & 3) << 2;
      const float4 a = *(const float4*)&A[(size_t)(row0 + m) * K + k0 + kq];
      As[kq + 0][m] = a.x; As[kq + 1][m] = a.y;
      As[kq + 2][m] = a.z; As[kq + 3][m] = a.w;
    }
#pragma unroll
    for (int i = 0; i < (BK * BN) / (256 * 4); ++i) {
      int s = tid + i * 256;
      int kk = s / (BN / 4);
      int nn = (s % (BN / 4)) << 2;
      int col = col0 + nn;
      const float* Brow = &B[(size_t)(k0 + kk) * N];
      float4 b;
      if (col + 3 < N) {
        b = *(const float4*)&Brow[col];
      } else {
        b.x = (col + 0 < N) ? Brow[col + 0] : 0.f;
        b.y = (col + 1 < N) ? Brow[col + 1] : 0.f;
        b.z = (col + 2 < N) ? Brow[col + 2] : 0.f;
        b.w = (col + 3 < N) ? Brow[col + 3] : 0.f;
      }
      *(float4*)&Bs[kk][nn] = b;
    }
    __syncthreads();

#pragma unroll
    for (int k = 0; k < BK; ++k) {
      float a[TM], b[TN];
      *(float4*)&a[0] = *(const float4*)&As[k][ty * 4];
      if constexpr (TM == 8)
        *(float4*)&a[4] = *(const float4*)&As[k][BM / 2 + ty * 4];
      *(float4*)&b[0] = *(const float4*)&Bs[k][tx * 4];
      if constexpr (TN == 8)
        *(float4*)&b[4] = *(const float4*)&Bs[k][BN / 2 + tx * 4];
#pragma unroll
      for (int i = 0; i < TM; ++i)
#pragma unroll
        for (int j = 0; j < TN; ++j) acc[i][j] += a[i] * b[j];
    }
    __syncthreads();
  }

#pragma unroll
  for (int i = 0; i < TM; ++i) {
    int row;
    if constexpr (TM == 8) row = row0 + ((i < 4) ? (ty * 4 + i) : (BM / 2 + ty * 4 + i - 4));
    else                   row = row0 + ty * 4 + i;
    float* Crow = &C[(size_t)row * N];
#pragma unroll
    for (int jq = 0; jq < TN / 4; ++jq) {
      int col;
      if constexpr (TN == 8) col = col0 + ((jq == 0) ? (tx * 4) : (BN / 2 + tx * 4));
      else                   col = col0 + tx * 4;
      if (col + 3 < N) {
        float4 r;
        r.x = acc[i][jq * 4 + 0] + bias[col + 0];
        r.y = acc[i][jq * 4 + 1] + bias[col + 1];
        r.z = acc[i][jq * 4 + 2] + bias[col + 2];
        r.w = acc[i][jq * 4 + 3] + bias[col + 3];
        *(float4*)&Crow[col] = r;
      } else {
#pragma unroll
        for (int j = 0; j < 4; ++j)
          if (col + j < N) Crow[col + j] = acc[i][jq * 4 + j] + bias[col + j];
      }
    }
  }
}

// Deformable sampling: one WAVE per pixel (n,hw); lane covers 4 channels
// (float4 gathers). lane>>4 = group, (lane&15)*4 = channel start in group.
// All 36 corner loads unconditional (clamped addr, weight zeroed via select).
// Padded-coord algebra: px = w+1+dx+off_x on the 66x66 zero-ring image;
// corner contributes iff it lies in the interior [1,64]^2.
__global__ __launch_bounds__(256) void dcn_sample4(const float* __restrict__ val,
    const float* __restrict__ off, const float* __restrict__ msk,
    float* __restrict__ out) {
  __shared__ float loff[4 * 72];
  __shared__ float lmsk[4 * 36];
  const int tid = threadIdx.x;
  const int pix0 = blockIdx.x * 4;

  { // stage offsets + masks for the block's 4 pixels (coalesced)
    const float* go = off + (size_t)pix0 * 72;
    for (int i = tid; i < 4 * 72; i += 256) loff[i] = go[i];
    const float* gm = msk + (size_t)pix0 * 36;
    if (tid < 4 * 36) lmsk[tid] = gm[tid];
  }
  __syncthreads();

  const int wid = tid >> 6;
  const int lane = tid & 63;
  const int pix = pix0 + wid;              // n*L + hw
  const int n = pix >> 12;                 // L = 4096
  const int hw = pix & (LSZ - 1);
  const int h = hw >> 6, w = hw & 63;
  const int g = lane >> 4;
  const int cs = (lane & 15) << 2;         // channel start within group

  const float* po = &loff[wid * 72 + g * 18];
  const float* pm = &lmsk[wid * 36 + g * 9];
  const float* vbase = val + (size_t)n * (LSZ * CHN) + g * GCH + cs;

  float4 acc = {0.f, 0.f, 0.f, 0.f};
#pragma unroll
  for (int p = 0; p < PTS; ++p) {
    const int dx = p / 3 - 1, dy = p % 3 - 1;  // x-major flatten (torch 'ij' over (w,h))
    const float2 o = *(const float2*)&po[p * 2];
    const float m = pm[p];
    const float px = (float)(w + 1 + dx) + o.x;
    const float py = (float)(h + 1 + dy) + o.y;
    const float fx = floorf(px), fy = floorf(py);
    const int x0 = (int)fx, y0 = (int)fy;
    const float wx = px - fx, wy = py - fy;
    const float cw0 = m * (1.f - wx) * (1.f - wy);
    const float cw1 = m * wx * (1.f - wy);
    const float cw2 = m * (1.f - wx) * wy;
    const float cw3 = m * wx * wy;
#pragma unroll
    for (int c = 0; c < 4; ++c) {
      const int xi = x0 + (c & 1), yi = y0 + (c >> 1);
      const float cw = (c == 0) ? cw0 : (c == 1) ? cw1 : (c == 2) ? cw2 : cw3;
      const bool valid = (xi >= 1) & (xi <= 64) & (yi >= 1) & (yi <= 64);
      const int sx = min(max(xi - 1, 0), 63);
      const int sy = min(max(yi - 1, 0), 63);
      const float wgt = valid ? cw : 0.f;
      const float4 v = *(const float4*)&vbase[(size_t)(sy * WSZ + sx) * CHN];
      acc.x += wgt * v.x; acc.y += wgt * v.y;
      acc.z += wgt * v.z; acc.w += wgt * v.w;
    }
  }
  *(float4*)&out[(size_t)pix * CHN + g * GCH + cs] = acc;
}

extern "C" void kernel_launch(void* const* d_in, const int* in_sizes, int n_in,
                              void* d_out, int out_size, void* d_ws, size_t ws_size,
                              hipStream_t stream) {
  const float* x        = (const float*)d_in[0];
  const float* w_value  = (const float*)d_in[1];
  const float* b_value  = (const float*)d_in[2];
  const float* w_offset = (const float*)d_in[3];
  const float* b_offset = (const float*)d_in[4];
  const float* w_mask   = (const float*)d_in[5];
  const float* b_mask   = (const float*)d_in[6];
  const float* w_out    = (const float*)d_in[7];
  const float* b_out    = (const float*)d_in[8];
  float* out = (float*)d_out;

  const int M = NBATCH * LSZ;          // 32768
  float* ws    = (float*)d_ws;
  float* value = ws;                               // M*256
  float* offv  = value + (size_t)M * CHN;          // M*72
  float* mskv  = offv  + (size_t)M * 72;           // M*36
  float* yv    = mskv  + (size_t)M * 36;           // M*256

  dim3 blk(256);
  // value GEMM: 32768 x 256 x 256 via split-bf16 MFMA
  gemm_mfma_split<<<dim3(CHN / 128, M / 128), blk, 0, stream>>>(
      x, w_value, b_value, value, M, CHN, CHN);
  // offset GEMM: 32768 x 72 x 256 (f32 VALU)
  gemm_bias<4, 4><<<dim3((72 + 63) / 64, M / 64), blk, 0, stream>>>(
      x, w_offset, b_offset, offv, M, 72, CHN);
  // mask GEMM: 32768 x 36 x 256 (f32 VALU)
  gemm_bias<4, 4><<<dim3((36 + 63) / 64, M / 64), blk, 0, stream>>>(
      x, w_mask, b_mask, mskv, M, 36, CHN);
  // deformable sampling: one wave per pixel, float4 per lane
  dcn_sample4<<<dim3(M / 4), blk, 0, stream>>>(value, offv, mskv, yv);
  // output GEMM: 32768 x 256 x 256 via split-bf16 MFMA
  gemm_mfma_split<<<dim3(CHN / 128, M / 128), blk, 0, stream>>>(
      yv, w_out, b_out, out, M, CHN, CHN);
}